// Round 15
// baseline (220.568 us; speedup 1.0000x reference)
//
#include <hip/hip_runtime.h>
#include <hip/hip_bf16.h>

#define CIN 512
#define OQK 64
#define NBATCH 4
#define NTOK 4096

typedef float f32x4 __attribute__((ext_vector_type(4)));
typedef _Float16 f16x8 __attribute__((ext_vector_type(8)));
typedef short s16x8 __attribute__((ext_vector_type(8)));
typedef unsigned short u16;
typedef unsigned int u32;
typedef u32 u32x2 __attribute__((ext_vector_type(2)));
typedef u16 u16x4 __attribute__((ext_vector_type(4)));

__device__ inline u16 f2bf(float f) {
    unsigned u = __float_as_uint(f);
    u += 0x7fffu + ((u >> 16) & 1u);
    return (u16)(u >> 16);
}
__device__ inline u16 f2h_bits(float f) {
    _Float16 h = (_Float16)f;
    return __builtin_bit_cast(unsigned short, h);
}

#define GLOAD16(gp, lp) __builtin_amdgcn_global_load_lds(                        \
    (const __attribute__((address_space(1))) void*)(gp),                         \
    (__attribute__((address_space(3))) void*)(lp), 16, 0, 0)

// ---------------- W f32 -> f16 pre-convert (into P-region alias) ----------------
__global__ __launch_bounds__(256) void wcvt(
    const float* __restrict__ Wq, const float* __restrict__ Wk,
    const float* __restrict__ Wv, u16* __restrict__ Wh)
{
    const size_t e0 = ((size_t)blockIdx.x * 256 + threadIdx.x) * 4;
    if (e0 >= 327680) return;
    const float* src; size_t off;
    if (e0 < 32768)      { src = Wq; off = e0; }
    else if (e0 < 65536) { src = Wk; off = e0 - 32768; }
    else                 { src = Wv; off = e0 - 65536; }
    f32x4 v = *reinterpret_cast<const f32x4*>(src + off);
    u16x4 h;
    #pragma unroll
    for (int j = 0; j < 4; ++j) h[j] = f2h_bits(v[j]);
    *reinterpret_cast<u16x4*>(Wh + e0) = h;
}

// ---------------- fused Q/K/V projections + x_s passthrough (r12-verified) ----------------
__global__ __launch_bounds__(512, 4) void proj_all(
    const float* __restrict__ x,
    const float* __restrict__ bq, const float* __restrict__ bk, const float* __restrict__ bv,
    const u16* __restrict__ Wh,
    u16* __restrict__ Qh, u16* __restrict__ Kh, u16* __restrict__ Vb,
    float* __restrict__ out)
{
    __shared__ u16 Ls[32 * 520];
    __shared__ u16 Lt[32 * 520];

    const int nb = blockIdx.x;   // 128 panels of 32 tokens
    const int b  = blockIdx.y;   // 4
    const int tid = threadIdx.x;
    const int w = tid >> 6, l = tid & 63;
    const int lr = l & 15, lg = l >> 4;
    const int n0 = nb * 32;

    const float* xs = x + (size_t)b * CIN * NTOK;
    const float* xt = x + (size_t)(b + NBATCH) * CIN * NTOK;
    float* os = out + (size_t)b * CIN * NTOK;

    // ---- stage both panels (threads 0-255: x_s + out copy; 256-511: x_t) ----
    {
        const int sg = tid >> 8, st = tid & 255;
        const int q = st & 7, cpb = st >> 3;     // n-quad, channel-pair base
        const float* src = sg ? xt : xs;
        u16* Lp = sg ? Lt : Ls;
        #pragma unroll
        for (int r = 0; r < 8; ++r) {
            const int c0 = (cpb + r * 32) * 2;
            f32x4 va = *reinterpret_cast<const f32x4*>(src + (size_t)c0 * NTOK + n0 + q * 4);
            f32x4 vb = *reinterpret_cast<const f32x4*>(src + (size_t)(c0 + 1) * NTOK + n0 + q * 4);
            if (!sg) {
                *reinterpret_cast<f32x4*>(os + (size_t)c0 * NTOK + n0 + q * 4) = va;
                *reinterpret_cast<f32x4*>(os + (size_t)(c0 + 1) * NTOK + n0 + q * 4) = vb;
            }
            #pragma unroll
            for (int j = 0; j < 4; ++j) {
                u32 pk = (u32)f2h_bits(va[j]) | ((u32)f2h_bits(vb[j]) << 16);
                *reinterpret_cast<u32*>(&Lp[(q * 4 + j) * 520 + c0]) = pk;
            }
        }
    }
    __syncthreads();

    const u16* Wq_ = Wh;
    const u16* Wk_ = Wh + 32768;
    const u16* Wv_ = Wh + 65536;
    const int cb = w * 64;
    const bool isq = (w < 4);
    const int h  = isq ? (w >> 1) : 0;            // Q: token-half
    const int ob = isq ? ((w & 1) * 2) : (w - 4); // Q: o-pair base; K: o-quarter

    f32x4 macc[4][2] = {};   // V accum [cf][fm]  (D[m][c] orientation)
    f32x4 xacc[2] = {};      // Q (i) or K (h2)   (D[o][n] orientation)

    #pragma unroll 4
    for (int t = 0; t < 16; ++t) {
        const int c0 = t * 32 + lg * 8;
        f16x8 X0 = *reinterpret_cast<const f16x8*>(&Lt[lr * 520 + c0]);
        f16x8 X1 = *reinterpret_cast<const f16x8*>(&Lt[(16 + lr) * 520 + c0]);
        #pragma unroll
        for (int cf = 0; cf < 4; ++cf) {
            f16x8 Wvf = *reinterpret_cast<const f16x8*>(&Wv_[(size_t)(cb + cf * 16 + lr) * CIN + c0]);
            macc[cf][0] = __builtin_amdgcn_mfma_f32_16x16x32_f16(X0, Wvf, macc[cf][0], 0, 0, 0);
            macc[cf][1] = __builtin_amdgcn_mfma_f32_16x16x32_f16(X1, Wvf, macc[cf][1], 0, 0, 0);
        }
        if (isq) {
            f16x8 Xs = *reinterpret_cast<const f16x8*>(&Ls[(h * 16 + lr) * 520 + c0]);
            #pragma unroll
            for (int i = 0; i < 2; ++i) {
                f16x8 Wqf = *reinterpret_cast<const f16x8*>(&Wq_[(size_t)((ob + i) * 16 + lr) * CIN + c0]);
                xacc[i] = __builtin_amdgcn_mfma_f32_16x16x32_f16(Wqf, Xs, xacc[i], 0, 0, 0);
            }
        } else {
            f16x8 Wkf = *reinterpret_cast<const f16x8*>(&Wk_[(size_t)(ob * 16 + lr) * CIN + c0]);
            xacc[0] = __builtin_amdgcn_mfma_f32_16x16x32_f16(Wkf, X0, xacc[0], 0, 0, 0);
            xacc[1] = __builtin_amdgcn_mfma_f32_16x16x32_f16(Wkf, X1, xacc[1], 0, 0, 0);
        }
    }

    // ---- V store: packed bf16x4 along m ----
    #pragma unroll
    for (int cf = 0; cf < 4; ++cf) {
        const int c = cb + cf * 16 + lr;
        const float bvc = bv[c];
        #pragma unroll
        for (int fm = 0; fm < 2; ++fm) {
            u16x4 pk;
            #pragma unroll
            for (int r = 0; r < 4; ++r) pk[r] = f2bf(macc[cf][fm][r] + bvc);
            *reinterpret_cast<u16x4*>(&Vb[((size_t)b * CIN + c) * NTOK + n0 + fm * 16 + lg * 4]) = pk;
        }
    }
    // ---- Q / K store: packed f16x4 along o ----
    if (isq) {
        #pragma unroll
        for (int i = 0; i < 2; ++i) {
            u16x4 pk;
            #pragma unroll
            for (int r = 0; r < 4; ++r) pk[r] = f2h_bits(xacc[i][r] + bq[(ob + i) * 16 + lg * 4 + r]);
            *reinterpret_cast<u16x4*>(&Qh[((size_t)b * NTOK + n0 + h * 16 + lr) * OQK + (ob + i) * 16 + lg * 4]) = pk;
        }
    } else {
        #pragma unroll
        for (int h2 = 0; h2 < 2; ++h2) {
            u16x4 pk;
            #pragma unroll
            for (int r = 0; r < 4; ++r) pk[r] = f2h_bits(xacc[h2][r] + bk[ob * 16 + lg * 4 + r]);
            *reinterpret_cast<u16x4*>(&Kh[((size_t)b * NTOK + n0 + h2 * 16 + lr) * OQK + ob * 16 + lg * 4]) = pk;
        }
    }
}

// ---------------- pass S: P = exp(K Q^T) (bf16, [b][n][m]) + exact den ----------------
// wave-local LDS transpose so P stores are 16B/lane, 128B-contiguous (r14-verified).

#define SLOADK(mt, KF)                                                          \
  { _Pragma("unroll")                                                           \
    for (int mf_ = 0; mf_ < 4; ++mf_) {                                         \
      const u16* kp = Kbase + (size_t)((mt) * 64 + mf_ * 16 + lr) * OQK + lg * 8; \
      KF[mf_][0] = *reinterpret_cast<const f16x8*>(kp);                         \
      KF[mf_][1] = *reinterpret_cast<const f16x8*>(kp + 32);                    \
    } }

#define STILE(mt, KF)                                                           \
  { _Pragma("unroll")                                                           \
    for (int mf_ = 0; mf_ < 4; ++mf_) {                                         \
      f32x4 s_ = {};                                                            \
      s_ = __builtin_amdgcn_mfma_f32_16x16x32_f16(KF[mf_][0], Bq0, s_, 0, 0, 0);\
      s_ = __builtin_amdgcn_mfma_f32_16x16x32_f16(KF[mf_][1], Bq1, s_, 0, 0, 0);\
      float p0 = __expf(s_[0]), p1 = __expf(s_[1]);                             \
      float p2 = __expf(s_[2]), p3 = __expf(s_[3]);                             \
      denl += (p0 + p1) + (p2 + p3);                                            \
      u32x2 pk;                                                                 \
      pk[0] = (u32)f2bf(p0) | ((u32)f2bf(p1) << 16);                            \
      pk[1] = (u32)f2bf(p2) | ((u32)f2bf(p3) << 16);                            \
      const int widx_ = (lr * 64 + mf_ * 16 + lg * 4) ^ ((lr & 7) << 3);        \
      *reinterpret_cast<u32x2*>(&Tw[widx_]) = pk;                               \
    }                                                                           \
    _Pragma("unroll")                                                           \
    for (int rr_ = 0; rr_ < 2; ++rr_) {                                         \
      const int nl_ = (l >> 3) + rr_ * 8;                                       \
      const int ridx_ = (nl_ * 64 + (l & 7) * 8) ^ ((nl_ & 7) << 3);            \
      s16x8 v_ = *reinterpret_cast<const s16x8*>(&Tw[ridx_]);                   \
      *reinterpret_cast<s16x8*>(&Pp[(size_t)(grp * 16 + nl_) * NTOK + (mt) * 64 + (l & 7) * 8]) = v_; \
    } }

__global__ __launch_bounds__(256, 4) void qk_exp(
    const u16* __restrict__ Qh, const u16* __restrict__ Kh,
    u16* __restrict__ P, float* __restrict__ den)
{
    __shared__ float dpart[4][16];
    __shared__ u16 T[4][1024];                     // per-wave 16x64 transpose tile
    const int g = blockIdx.x;
    const int xcd = g & 7;
    const int b = xcd >> 1;
    const int grp = ((g >> 3) << 1) | (xcd & 1);   // 16-row group (0..255)

    const int tid = threadIdx.x;
    const int w = tid >> 6, l = tid & 63;
    const int lr = l & 15, lg = l >> 4;

    const int n = grp * 16 + lr;
    const int mbase = w * 1024;                    // wave's m-quarter
    const u16* Kbase = Kh + ((size_t)b * NTOK + mbase) * OQK;
    u16* Pp = P + (size_t)b * NTOK * NTOK + mbase;
    u16* Tw = T[w];

    f16x8 Bq0, Bq1;
    {
        const u16* qp = Qh + ((size_t)b * NTOK + n) * OQK + lg * 8;
        Bq0 = *reinterpret_cast<const f16x8*>(qp);
        Bq1 = *reinterpret_cast<const f16x8*>(qp + 32);
    }

    float denl = 0.f;
    f16x8 KfA[4][2], KfB[4][2];

    SLOADK(0, KfA);
    for (int mt = 0; mt < 16; mt += 2) {
        SLOADK(mt + 1, KfB);
        STILE(mt, KfA);
        if (mt + 2 < 16) SLOADK(mt + 2, KfA);
        STILE(mt + 1, KfB);
    }

    denl += __shfl_xor(denl, 16);
    denl += __shfl_xor(denl, 32);
    if (l < 16) dpart[w][l] = denl;
    __syncthreads();
    if (tid < 16)
        den[(size_t)b * NTOK + grp * 16 + tid] =
            (dpart[0][tid] + dpart[1][tid]) + (dpart[2][tid] + dpart[3][tid]);
}

// ---------------- pass PV: out = x_t + (V P^T) / den ----------------
// 128x128 tile, 4 waves, 4 LDS bufs, 3-deep prefetch, counted vmcnt(8),
// verified swizzle, XCD P-sharing map. NEW (r15): MFMA operands SWAPPED
// (A=P-frag rows n, B=V-frag rows c) -> D[n][c]: the register axis runs
// along n (contiguous in out), so the epilogue becomes 16 f32x4 load/store
// pairs per thread (was 64 scalar pairs). Fragment LDS reads are unchanged.

#define PVSTAGE(BUF, m0)                                                        \
  { _Pragma("unroll")                                                           \
    for (int i_ = 0; i_ < 2; ++i_) {                                            \
      const int chunk_ = i_ * 256 + tid;                                        \
      const int row_ = chunk_ >> 2;                                             \
      const int sl_ = (chunk_ & 3) ^ ((row_ >> 1) & 3);                         \
      GLOAD16(Abase + (size_t)row_ * NTOK + (m0) + sl_ * 8,                     \
              &AS[(BUF) * 4096 + chunk_ * 8]);                                  \
    }                                                                           \
    _Pragma("unroll")                                                           \
    for (int j_ = 0; j_ < 2; ++j_) {                                            \
      const int chunk_ = j_ * 256 + tid;                                        \
      const int row_ = chunk_ >> 2;                                             \
      const int sl_ = (chunk_ & 3) ^ ((row_ >> 1) & 3);                         \
      GLOAD16(Bbase + (size_t)row_ * NTOK + (m0) + sl_ * 8,                     \
              &BS[(BUF) * 4096 + chunk_ * 8]);                                  \
    } }

#define PVBODY(CUR, kt, DOSTAGE, VM)                                            \
  {                                                                             \
    asm volatile("s_waitcnt vmcnt(" VM ")" ::: "memory");                       \
    __builtin_amdgcn_s_barrier();                                               \
    if (DOSTAGE) PVSTAGE(((kt) + 3) & 3, ((kt) + 3) * 32);                      \
    s16x8 Af[4], Bf[4];                                                         \
    const int swz_ = ((lr >> 1) & 3) << 3;                                      \
    _Pragma("unroll")                                                           \
    for (int f_ = 0; f_ < 4; ++f_) {                                            \
      Af[f_] = *(const s16x8*)&AS[(CUR) * 4096 + (wr * 64 + f_ * 16 + lr) * 32 + ((lg * 8) ^ swz_)]; \
      Bf[f_] = *(const s16x8*)&BS[(CUR) * 4096 + (wc * 64 + f_ * 16 + lr) * 32 + ((lg * 8) ^ swz_)]; \
    }                                                                           \
    __builtin_amdgcn_s_setprio(1);                                              \
    _Pragma("unroll")                                                           \
    for (int nf_ = 0; nf_ < 4; ++nf_)                                           \
      _Pragma("unroll")                                                         \
      for (int cf_ = 0; cf_ < 4; ++cf_)                                         \
        acc[nf_][cf_] = __builtin_amdgcn_mfma_f32_16x16x32_bf16(Bf[nf_], Af[cf_], acc[nf_][cf_], 0, 0, 0); \
    __builtin_amdgcn_s_setprio(0);                                              \
  }

__global__ __launch_bounds__(256, 2) void pv(
    const float* __restrict__ x, const u16* __restrict__ Vb,
    const u16* __restrict__ P, const float* __restrict__ den,
    float* __restrict__ out)
{
    __shared__ u16 AS[4 * 4096];   // 4 bufs x 128rows x 32k  (V)
    __shared__ u16 BS[4 * 4096];   // 4 bufs x 128rows x 32k  (P)

    const int g = blockIdx.x;
    const int xcd = g & 7;
    const int b = xcd >> 1;
    const int idx = ((g >> 3) << 1) | (xcd & 1);  // 0..127 per batch
    const int bm = (idx >> 1) & 3;                // c-tile: sharers same XCD
    const int bn = ((idx >> 3) << 1) | (idx & 1); // n-tile 0..31

    const int tid = threadIdx.x;
    const int w = tid >> 6, l = tid & 63;
    const int lr = l & 15, lg = l >> 4;
    const int wr = w >> 1, wc = w & 1;            // wave quadrant: 64c x 64n

    const u16* Abase = Vb + (size_t)b * CIN * NTOK + (size_t)(bm * 128) * NTOK;
    const u16* Bbase = P + (size_t)b * NTOK * NTOK + (size_t)(bn * 128) * NTOK;

    f32x4 acc[4][4] = {};                         // [nf][cf]  (D rows = n)

    PVSTAGE(0, 0);
    PVSTAGE(1, 32);
    PVSTAGE(2, 64);
    for (int kt2 = 0; kt2 < 124; kt2 += 4) {
        PVBODY(0, kt2 + 0, true, "8");
        PVBODY(1, kt2 + 1, true, "8");
        PVBODY(2, kt2 + 2, true, "8");
        PVBODY(3, kt2 + 3, true, "8");
    }
    PVBODY(0, 124, true,  "8");
    PVBODY(1, 125, false, "8");
    PVBODY(2, 126, false, "4");
    PVBODY(3, 127, false, "0");

    // epilogue: out = x_t + acc / den[n] -- f32x4 along n (register axis)
    const float* denb = den + (size_t)b * NTOK;
    float invv[4][4];
    #pragma unroll
    for (int nf = 0; nf < 4; ++nf)
        #pragma unroll
        for (int r = 0; r < 4; ++r)
            invv[nf][r] = 1.0f / denb[bn * 128 + wc * 64 + nf * 16 + lg * 4 + r];

    const float* xtp = x + (size_t)(b + NBATCH) * CIN * NTOK;
    float* op = out + (size_t)(b + NBATCH) * CIN * NTOK;
    #pragma unroll
    for (int nf = 0; nf < 4; ++nf) {
        const int n = bn * 128 + wc * 64 + nf * 16 + lg * 4;
        #pragma unroll
        for (int cf = 0; cf < 4; ++cf) {
            const int c = bm * 128 + wr * 64 + cf * 16 + lr;
            const size_t idx2 = (size_t)c * NTOK + n;
            f32x4 xv = *reinterpret_cast<const f32x4*>(xtp + idx2);
            f32x4 o;
            #pragma unroll
            for (int r = 0; r < 4; ++r) o[r] = xv[r] + acc[nf][cf][r] * invv[nf][r];
            *reinterpret_cast<f32x4*>(op + idx2) = o;
        }
    }
}

extern "C" void kernel_launch(void* const* d_in, const int* in_sizes, int n_in,
                              void* d_out, int out_size, void* d_ws, size_t ws_size,
                              hipStream_t stream)
{
    (void)in_sizes; (void)n_in; (void)out_size; (void)ws_size;
    const float* x  = (const float*)d_in[0];
    const float* Wq = (const float*)d_in[1];
    const float* bq = (const float*)d_in[2];
    const float* Wk = (const float*)d_in[3];
    const float* bk = (const float*)d_in[4];
    const float* Wv = (const float*)d_in[5];
    const float* bv = (const float*)d_in[6];
    float* out = (float*)d_out;

    // ws layout (~148.1 MB): Qh 2MB | Kh 2MB | Vb 16MB | den 64KB | P 128MB
    // Wh (f16 weights, 640KB) aliases the head of P (dead before qk_exp writes P).
    u16* Qh = (u16*)d_ws;
    u16* Kh = Qh + (size_t)NBATCH * NTOK * OQK;
    u16* Vb = Kh + (size_t)NBATCH * NTOK * OQK;
    float* den = (float*)(Vb + (size_t)NBATCH * CIN * NTOK);
    u16* P  = (u16*)(den + (size_t)NBATCH * NTOK);
    u16* Wh = P;

    wcvt    <<<320, 256, 0, stream>>>(Wq, Wk, Wv, Wh);
    proj_all<<<dim3(128, NBATCH), 512, 0, stream>>>(x, bq, bk, bv, Wh, Qh, Kh, Vb, out);
    qk_exp  <<<1024, 256, 0, stream>>>(Qh, Kh, P, den);
    pv      <<<512, 256, 0, stream>>>(x, Vb, P, den, out);
}

// Round 16
// 217.841 us; speedup vs baseline: 1.0125x; 1.0125x over previous
//
#include <hip/hip_runtime.h>
#include <hip/hip_bf16.h>

#define CIN 512
#define OQK 64
#define NBATCH 4
#define NTOK 4096
#define L2E 1.44269504088896f

typedef float f32x4 __attribute__((ext_vector_type(4)));
typedef _Float16 f16x8 __attribute__((ext_vector_type(8)));
typedef short s16x8 __attribute__((ext_vector_type(8)));
typedef unsigned short u16;
typedef unsigned int u32;
typedef u32 u32x2 __attribute__((ext_vector_type(2)));
typedef u16 u16x4 __attribute__((ext_vector_type(4)));

__device__ inline u16 f2bf(float f) {
    unsigned u = __float_as_uint(f);
    u += 0x7fffu + ((u >> 16) & 1u);
    return (u16)(u >> 16);
}
__device__ inline u16 f2h_bits(float f) {
    _Float16 h = (_Float16)f;
    return __builtin_bit_cast(unsigned short, h);
}
// packed f32x2 -> bf16x2 (RTNE, same bits as f2bf) in ONE VALU op
__device__ inline u32 cvtpk_bf16(float lo, float hi) {
    u32 r;
    asm("v_cvt_pk_bf16_f32 %0, %1, %2" : "=v"(r) : "v"(lo), "v"(hi));
    return r;
}

#define GLOAD16(gp, lp) __builtin_amdgcn_global_load_lds(                        \
    (const __attribute__((address_space(1))) void*)(gp),                         \
    (__attribute__((address_space(3))) void*)(lp), 16, 0, 0)

// ---------------- W f32 -> f16 pre-convert (into P-region alias) ----------------
__global__ __launch_bounds__(256) void wcvt(
    const float* __restrict__ Wq, const float* __restrict__ Wk,
    const float* __restrict__ Wv, u16* __restrict__ Wh)
{
    const size_t e0 = ((size_t)blockIdx.x * 256 + threadIdx.x) * 4;
    if (e0 >= 327680) return;
    const float* src; size_t off;
    if (e0 < 32768)      { src = Wq; off = e0; }
    else if (e0 < 65536) { src = Wk; off = e0 - 32768; }
    else                 { src = Wv; off = e0 - 65536; }
    f32x4 v = *reinterpret_cast<const f32x4*>(src + off);
    u16x4 h;
    #pragma unroll
    for (int j = 0; j < 4; ++j) h[j] = f2h_bits(v[j]);
    *reinterpret_cast<u16x4*>(Wh + e0) = h;
}

// ---------------- fused Q/K/V projections + x_s passthrough ----------------
// r12-verified structure. NEW (r16): Q pre-scaled by log2(e) so qk_exp can use
// native exp2 (v_exp_f32) without a per-element multiply; V bf16 pack via cvt_pk.
__global__ __launch_bounds__(512, 4) void proj_all(
    const float* __restrict__ x,
    const float* __restrict__ bq, const float* __restrict__ bk, const float* __restrict__ bv,
    const u16* __restrict__ Wh,
    u16* __restrict__ Qh, u16* __restrict__ Kh, u16* __restrict__ Vb,
    float* __restrict__ out)
{
    __shared__ u16 Ls[32 * 520];
    __shared__ u16 Lt[32 * 520];

    const int nb = blockIdx.x;   // 128 panels of 32 tokens
    const int b  = blockIdx.y;   // 4
    const int tid = threadIdx.x;
    const int w = tid >> 6, l = tid & 63;
    const int lr = l & 15, lg = l >> 4;
    const int n0 = nb * 32;

    const float* xs = x + (size_t)b * CIN * NTOK;
    const float* xt = x + (size_t)(b + NBATCH) * CIN * NTOK;
    float* os = out + (size_t)b * CIN * NTOK;

    // ---- stage both panels (threads 0-255: x_s + out copy; 256-511: x_t) ----
    {
        const int sg = tid >> 8, st = tid & 255;
        const int q = st & 7, cpb = st >> 3;     // n-quad, channel-pair base
        const float* src = sg ? xt : xs;
        u16* Lp = sg ? Lt : Ls;
        #pragma unroll
        for (int r = 0; r < 8; ++r) {
            const int c0 = (cpb + r * 32) * 2;
            f32x4 va = *reinterpret_cast<const f32x4*>(src + (size_t)c0 * NTOK + n0 + q * 4);
            f32x4 vb = *reinterpret_cast<const f32x4*>(src + (size_t)(c0 + 1) * NTOK + n0 + q * 4);
            if (!sg) {
                *reinterpret_cast<f32x4*>(os + (size_t)c0 * NTOK + n0 + q * 4) = va;
                *reinterpret_cast<f32x4*>(os + (size_t)(c0 + 1) * NTOK + n0 + q * 4) = vb;
            }
            #pragma unroll
            for (int j = 0; j < 4; ++j) {
                u32 pk = (u32)f2h_bits(va[j]) | ((u32)f2h_bits(vb[j]) << 16);
                *reinterpret_cast<u32*>(&Lp[(q * 4 + j) * 520 + c0]) = pk;
            }
        }
    }
    __syncthreads();

    const u16* Wq_ = Wh;
    const u16* Wk_ = Wh + 32768;
    const u16* Wv_ = Wh + 65536;
    const int cb = w * 64;
    const bool isq = (w < 4);
    const int h  = isq ? (w >> 1) : 0;            // Q: token-half
    const int ob = isq ? ((w & 1) * 2) : (w - 4); // Q: o-pair base; K: o-quarter

    f32x4 macc[4][2] = {};   // V accum [cf][fm]  (D[m][c] orientation)
    f32x4 xacc[2] = {};      // Q (i) or K (h2)   (D[o][n] orientation)

    #pragma unroll 4
    for (int t = 0; t < 16; ++t) {
        const int c0 = t * 32 + lg * 8;
        f16x8 X0 = *reinterpret_cast<const f16x8*>(&Lt[lr * 520 + c0]);
        f16x8 X1 = *reinterpret_cast<const f16x8*>(&Lt[(16 + lr) * 520 + c0]);
        #pragma unroll
        for (int cf = 0; cf < 4; ++cf) {
            f16x8 Wvf = *reinterpret_cast<const f16x8*>(&Wv_[(size_t)(cb + cf * 16 + lr) * CIN + c0]);
            macc[cf][0] = __builtin_amdgcn_mfma_f32_16x16x32_f16(X0, Wvf, macc[cf][0], 0, 0, 0);
            macc[cf][1] = __builtin_amdgcn_mfma_f32_16x16x32_f16(X1, Wvf, macc[cf][1], 0, 0, 0);
        }
        if (isq) {
            f16x8 Xs = *reinterpret_cast<const f16x8*>(&Ls[(h * 16 + lr) * 520 + c0]);
            #pragma unroll
            for (int i = 0; i < 2; ++i) {
                f16x8 Wqf = *reinterpret_cast<const f16x8*>(&Wq_[(size_t)((ob + i) * 16 + lr) * CIN + c0]);
                xacc[i] = __builtin_amdgcn_mfma_f32_16x16x32_f16(Wqf, Xs, xacc[i], 0, 0, 0);
            }
        } else {
            f16x8 Wkf = *reinterpret_cast<const f16x8*>(&Wk_[(size_t)(ob * 16 + lr) * CIN + c0]);
            xacc[0] = __builtin_amdgcn_mfma_f32_16x16x32_f16(Wkf, X0, xacc[0], 0, 0, 0);
            xacc[1] = __builtin_amdgcn_mfma_f32_16x16x32_f16(Wkf, X1, xacc[1], 0, 0, 0);
        }
    }

    // ---- V store: packed bf16x4 along m (cvt_pk) ----
    #pragma unroll
    for (int cf = 0; cf < 4; ++cf) {
        const int c = cb + cf * 16 + lr;
        const float bvc = bv[c];
        #pragma unroll
        for (int fm = 0; fm < 2; ++fm) {
            u32x2 pk;
            pk[0] = cvtpk_bf16(macc[cf][fm][0] + bvc, macc[cf][fm][1] + bvc);
            pk[1] = cvtpk_bf16(macc[cf][fm][2] + bvc, macc[cf][fm][3] + bvc);
            *reinterpret_cast<u32x2*>(&Vb[((size_t)b * CIN + c) * NTOK + n0 + fm * 16 + lg * 4]) = pk;
        }
    }
    // ---- Q / K store: packed f16x4 along o.  Q scaled by log2(e). ----
    if (isq) {
        #pragma unroll
        for (int i = 0; i < 2; ++i) {
            u16x4 pk;
            #pragma unroll
            for (int r = 0; r < 4; ++r)
                pk[r] = f2h_bits((xacc[i][r] + bq[(ob + i) * 16 + lg * 4 + r]) * L2E);
            *reinterpret_cast<u16x4*>(&Qh[((size_t)b * NTOK + n0 + h * 16 + lr) * OQK + (ob + i) * 16 + lg * 4]) = pk;
        }
    } else {
        #pragma unroll
        for (int h2 = 0; h2 < 2; ++h2) {
            u16x4 pk;
            #pragma unroll
            for (int r = 0; r < 4; ++r) pk[r] = f2h_bits(xacc[h2][r] + bk[ob * 16 + lg * 4 + r]);
            *reinterpret_cast<u16x4*>(&Kh[((size_t)b * NTOK + n0 + h2 * 16 + lr) * OQK + ob * 16 + lg * 4]) = pk;
        }
    }
}

// ---------------- pass S: P = exp(K Q^T) (bf16, [b][n][m]) + exact den ----------------
// wave-local LDS transpose (r14-verified). NEW (r16): exp2 (Q pre-scaled) and
// cvt_pk packing -- ~4.5 fewer VALU ops per P element, identical values.

#define SLOADK(mt, KF)                                                          \
  { _Pragma("unroll")                                                           \
    for (int mf_ = 0; mf_ < 4; ++mf_) {                                         \
      const u16* kp = Kbase + (size_t)((mt) * 64 + mf_ * 16 + lr) * OQK + lg * 8; \
      KF[mf_][0] = *reinterpret_cast<const f16x8*>(kp);                         \
      KF[mf_][1] = *reinterpret_cast<const f16x8*>(kp + 32);                    \
    } }

#define STILE(mt, KF)                                                           \
  { _Pragma("unroll")                                                           \
    for (int mf_ = 0; mf_ < 4; ++mf_) {                                         \
      f32x4 s_ = {};                                                            \
      s_ = __builtin_amdgcn_mfma_f32_16x16x32_f16(KF[mf_][0], Bq0, s_, 0, 0, 0);\
      s_ = __builtin_amdgcn_mfma_f32_16x16x32_f16(KF[mf_][1], Bq1, s_, 0, 0, 0);\
      float p0 = exp2f(s_[0]), p1 = exp2f(s_[1]);                               \
      float p2 = exp2f(s_[2]), p3 = exp2f(s_[3]);                               \
      denl += (p0 + p1) + (p2 + p3);                                            \
      u32x2 pk;                                                                 \
      pk[0] = cvtpk_bf16(p0, p1);                                               \
      pk[1] = cvtpk_bf16(p2, p3);                                               \
      const int widx_ = (lr * 64 + mf_ * 16 + lg * 4) ^ ((lr & 7) << 3);        \
      *reinterpret_cast<u32x2*>(&Tw[widx_]) = pk;                               \
    }                                                                           \
    _Pragma("unroll")                                                           \
    for (int rr_ = 0; rr_ < 2; ++rr_) {                                         \
      const int nl_ = (l >> 3) + rr_ * 8;                                       \
      const int ridx_ = (nl_ * 64 + (l & 7) * 8) ^ ((nl_ & 7) << 3);            \
      s16x8 v_ = *reinterpret_cast<const s16x8*>(&Tw[ridx_]);                   \
      *reinterpret_cast<s16x8*>(&Pp[(size_t)(grp * 16 + nl_) * NTOK + (mt) * 64 + (l & 7) * 8]) = v_; \
    } }

__global__ __launch_bounds__(256, 4) void qk_exp(
    const u16* __restrict__ Qh, const u16* __restrict__ Kh,
    u16* __restrict__ P, float* __restrict__ den)
{
    __shared__ float dpart[4][16];
    __shared__ u16 T[4][1024];                     // per-wave 16x64 transpose tile
    const int g = blockIdx.x;
    const int xcd = g & 7;
    const int b = xcd >> 1;
    const int grp = ((g >> 3) << 1) | (xcd & 1);   // 16-row group (0..255)

    const int tid = threadIdx.x;
    const int w = tid >> 6, l = tid & 63;
    const int lr = l & 15, lg = l >> 4;

    const int n = grp * 16 + lr;
    const int mbase = w * 1024;                    // wave's m-quarter
    const u16* Kbase = Kh + ((size_t)b * NTOK + mbase) * OQK;
    u16* Pp = P + (size_t)b * NTOK * NTOK + mbase;
    u16* Tw = T[w];

    f16x8 Bq0, Bq1;
    {
        const u16* qp = Qh + ((size_t)b * NTOK + n) * OQK + lg * 8;
        Bq0 = *reinterpret_cast<const f16x8*>(qp);
        Bq1 = *reinterpret_cast<const f16x8*>(qp + 32);
    }

    float denl = 0.f;
    f16x8 KfA[4][2], KfB[4][2];

    SLOADK(0, KfA);
    for (int mt = 0; mt < 16; mt += 2) {
        SLOADK(mt + 1, KfB);
        STILE(mt, KfA);
        if (mt + 2 < 16) SLOADK(mt + 2, KfA);
        STILE(mt + 1, KfB);
    }

    denl += __shfl_xor(denl, 16);
    denl += __shfl_xor(denl, 32);
    if (l < 16) dpart[w][l] = denl;
    __syncthreads();
    if (tid < 16)
        den[(size_t)b * NTOK + grp * 16 + tid] =
            (dpart[0][tid] + dpart[1][tid]) + (dpart[2][tid] + dpart[3][tid]);
}

// ---------------- pass PV: out = x_t + (V P^T) / den (r14-verified, ~96 us) ----------------

#define PVSTAGE(BUF, m0)                                                        \
  { _Pragma("unroll")                                                           \
    for (int i_ = 0; i_ < 2; ++i_) {                                            \
      const int chunk_ = i_ * 256 + tid;                                        \
      const int row_ = chunk_ >> 2;                                             \
      const int sl_ = (chunk_ & 3) ^ ((row_ >> 1) & 3);                         \
      GLOAD16(Abase + (size_t)row_ * NTOK + (m0) + sl_ * 8,                     \
              &AS[(BUF) * 4096 + chunk_ * 8]);                                  \
    }                                                                           \
    _Pragma("unroll")                                                           \
    for (int j_ = 0; j_ < 2; ++j_) {                                            \
      const int chunk_ = j_ * 256 + tid;                                        \
      const int row_ = chunk_ >> 2;                                             \
      const int sl_ = (chunk_ & 3) ^ ((row_ >> 1) & 3);                         \
      GLOAD16(Bbase + (size_t)row_ * NTOK + (m0) + sl_ * 8,                     \
              &BS[(BUF) * 4096 + chunk_ * 8]);                                  \
    } }

#define PVBODY(CUR, kt, DOSTAGE, VM)                                            \
  {                                                                             \
    asm volatile("s_waitcnt vmcnt(" VM ")" ::: "memory");                       \
    __builtin_amdgcn_s_barrier();                                               \
    if (DOSTAGE) PVSTAGE(((kt) + 3) & 3, ((kt) + 3) * 32);                      \
    s16x8 Af[4], Bf[4];                                                         \
    const int swz_ = ((lr >> 1) & 3) << 3;                                      \
    _Pragma("unroll")                                                           \
    for (int f_ = 0; f_ < 4; ++f_) {                                            \
      Af[f_] = *(const s16x8*)&AS[(CUR) * 4096 + (wr * 64 + f_ * 16 + lr) * 32 + ((lg * 8) ^ swz_)]; \
      Bf[f_] = *(const s16x8*)&BS[(CUR) * 4096 + (wc * 64 + f_ * 16 + lr) * 32 + ((lg * 8) ^ swz_)]; \
    }                                                                           \
    __builtin_amdgcn_s_setprio(1);                                              \
    _Pragma("unroll")                                                           \
    for (int cf_ = 0; cf_ < 4; ++cf_)                                           \
      _Pragma("unroll")                                                         \
      for (int nf_ = 0; nf_ < 4; ++nf_)                                         \
        acc[cf_][nf_] = __builtin_amdgcn_mfma_f32_16x16x32_bf16(Af[cf_], Bf[nf_], acc[cf_][nf_], 0, 0, 0); \
    __builtin_amdgcn_s_setprio(0);                                              \
  }

__global__ __launch_bounds__(256, 2) void pv(
    const float* __restrict__ x, const u16* __restrict__ Vb,
    const u16* __restrict__ P, const float* __restrict__ den,
    float* __restrict__ out)
{
    __shared__ u16 AS[4 * 4096];   // 4 bufs x 128rows x 32k  (V)
    __shared__ u16 BS[4 * 4096];   // 4 bufs x 128rows x 32k  (P)

    const int g = blockIdx.x;
    const int xcd = g & 7;
    const int b = xcd >> 1;
    const int idx = ((g >> 3) << 1) | (xcd & 1);  // 0..127 per batch
    const int bm = (idx >> 1) & 3;                // c-tile: sharers same XCD
    const int bn = ((idx >> 3) << 1) | (idx & 1); // n-tile 0..31

    const int tid = threadIdx.x;
    const int w = tid >> 6, l = tid & 63;
    const int lr = l & 15, lg = l >> 4;
    const int wr = w >> 1, wc = w & 1;            // wave quadrant: 64c x 64n

    const u16* Abase = Vb + (size_t)b * CIN * NTOK + (size_t)(bm * 128) * NTOK;
    const u16* Bbase = P + (size_t)b * NTOK * NTOK + (size_t)(bn * 128) * NTOK;

    f32x4 acc[4][4] = {};                         // [cf][nf]

    PVSTAGE(0, 0);
    PVSTAGE(1, 32);
    PVSTAGE(2, 64);
    for (int kt2 = 0; kt2 < 124; kt2 += 4) {
        PVBODY(0, kt2 + 0, true, "8");
        PVBODY(1, kt2 + 1, true, "8");
        PVBODY(2, kt2 + 2, true, "8");
        PVBODY(3, kt2 + 3, true, "8");
    }
    PVBODY(0, 124, true,  "8");
    PVBODY(1, 125, false, "8");
    PVBODY(2, 126, false, "4");
    PVBODY(3, 127, false, "0");

    // epilogue: out = x_t + acc / den[n]
    const float* denb = den + (size_t)b * NTOK;
    float inv[4];
    #pragma unroll
    for (int nf = 0; nf < 4; ++nf) inv[nf] = 1.0f / denb[bn * 128 + wc * 64 + nf * 16 + lr];

    const float* xtp = x + (size_t)(b + NBATCH) * CIN * NTOK;
    float* op = out + (size_t)(b + NBATCH) * CIN * NTOK;
    #pragma unroll
    for (int cf = 0; cf < 4; ++cf) {
        #pragma unroll
        for (int nf = 0; nf < 4; ++nf) {
            #pragma unroll
            for (int r = 0; r < 4; ++r) {
                const int c = bm * 128 + wr * 64 + cf * 16 + lg * 4 + r;
                const int n = bn * 128 + wc * 64 + nf * 16 + lr;
                const size_t idx2 = (size_t)c * NTOK + n;
                op[idx2] = xtp[idx2] + acc[cf][nf][r] * inv[nf];
            }
        }
    }
}

extern "C" void kernel_launch(void* const* d_in, const int* in_sizes, int n_in,
                              void* d_out, int out_size, void* d_ws, size_t ws_size,
                              hipStream_t stream)
{
    (void)in_sizes; (void)n_in; (void)out_size; (void)ws_size;
    const float* x  = (const float*)d_in[0];
    const float* Wq = (const float*)d_in[1];
    const float* bq = (const float*)d_in[2];
    const float* Wk = (const float*)d_in[3];
    const float* bk = (const float*)d_in[4];
    const float* Wv = (const float*)d_in[5];
    const float* bv = (const float*)d_in[6];
    float* out = (float*)d_out;

    // ws layout (~148.1 MB): Qh 2MB | Kh 2MB | Vb 16MB | den 64KB | P 128MB
    // Wh (f16 weights, 640KB) aliases the head of P (dead before qk_exp writes P).
    u16* Qh = (u16*)d_ws;
    u16* Kh = Qh + (size_t)NBATCH * NTOK * OQK;
    u16* Vb = Kh + (size_t)NBATCH * NTOK * OQK;
    float* den = (float*)(Vb + (size_t)NBATCH * CIN * NTOK);
    u16* P  = (u16*)(den + (size_t)NBATCH * NTOK);
    u16* Wh = P;

    wcvt    <<<320, 256, 0, stream>>>(Wq, Wk, Wv, Wh);
    proj_all<<<dim3(128, NBATCH), 512, 0, stream>>>(x, bq, bk, bv, Wh, Qh, Kh, Vb, out);
    qk_exp  <<<1024, 256, 0, stream>>>(Qh, Kh, P, den);
    pv      <<<512, 256, 0, stream>>>(x, Vb, P, den, out);
}